// Round 1
// baseline (1017.607 us; speedup 1.0000x reference)
//
#include <hip/hip_runtime.h>
#include <hip/hip_bf16.h>

// GEMM: out[256,1000] = X[256,150528] * C[1000,150528]^T  (fp32 in/out)
// R3: BM=256 (C read ONCE from HBM; X re-reads LLC-served), BN=128, 8 waves,
// double-buffered LDS (1 barrier/iter), clamped OOB B-rows (no zero-fill),
// split-K=96 with fp32 atomicAdd reduction.

#define BM 256
#define BN 128
#define BK 32
#define LDSS 40               // 32 + 8 pad (bf16 units); row = 80 B
#define SPLIT 96
#define NCLS 1000
#define DIM 150528
#define DCHUNK (DIM / SPLIT)  // 1568
#define KITERS (DCHUNK / BK)  // 49 exact

typedef short bf16x8 __attribute__((ext_vector_type(8)));
typedef float f32x4 __attribute__((ext_vector_type(4)));

static __device__ __forceinline__ unsigned short f2bf(float f) {
    union { __hip_bfloat16 h; unsigned short u; } cv;
    cv.h = __float2bfloat16(f);
    return cv.u;
}

__global__ __launch_bounds__(512, 4) void classifier_gemm(
    const float* __restrict__ X, const float* __restrict__ W,
    float* __restrict__ out)
{
    // double-buffered bf16 tiles: As 2*256*40*2B = 40 KB, Bs 2*128*40*2B = 20 KB
    __shared__ unsigned short As[2][BM * LDSS];
    __shared__ unsigned short Bs[2][BN * LDSS];

    const int t    = threadIdx.x;
    const int lane = t & 63;
    const int wave = t >> 6;      // 0..7
    const int wm   = wave >> 1;   // 0..3 (M quarter: 64 rows)
    const int wn   = wave & 1;    // 0..1 (N half: 64 cols)

    const int bj   = blockIdx.x;  // N tile: 0..7
    const int s    = blockIdx.y;  // D chunk: 0..95
    const int col0 = bj * BN;
    const size_t d0 = (size_t)s * DCHUNK;

    // ---- coalesced staging map: lane groups of 8 cover one 128 B row-segment.
    //      frow = t>>3 (0..63), fcol = (t&7)*4 floats (16 B).
    const int frow = t >> 3;
    const int fcol = (t & 7) * 4;

    const float* aptr = X + (size_t)frow * DIM + d0 + fcol;   // rows frow+64k, k=0..3
    const float* bptr[2];                                     // rows col0+frow+64k, k=0..1
    #pragma unroll
    for (int k = 0; k < 2; ++k) {
        int br = col0 + 64 * k + frow;
        if (br >= NCLS) br = NCLS - 1;   // clamp: garbage cols >=1000 never stored
        bptr[k] = W + (size_t)br * DIM + d0 + fcol;
    }

    f32x4 acc[4][4];
    #pragma unroll
    for (int i = 0; i < 4; ++i)
        #pragma unroll
        for (int j = 0; j < 4; ++j)
            acc[i][j] = (f32x4){0.f, 0.f, 0.f, 0.f};

    // LDS offsets (ushort units)
    const int w_off = frow * LDSS + (t & 7) * 4;
    const int a_off = (wm * 64 + (lane & 15)) * LDSS + (lane >> 4) * 8;
    const int b_off = (wn * 64 + (lane & 15)) * LDSS + (lane >> 4) * 8;

    float4 av[4], bv[2];

    auto stage = [&](int buf) {
        #pragma unroll
        for (int k = 0; k < 4; ++k) {
            ushort4 p;
            p.x = f2bf(av[k].x); p.y = f2bf(av[k].y);
            p.z = f2bf(av[k].z); p.w = f2bf(av[k].w);
            *(ushort4*)&As[buf][w_off + 64 * k * LDSS] = p;
        }
        #pragma unroll
        for (int k = 0; k < 2; ++k) {
            ushort4 p;
            p.x = f2bf(bv[k].x); p.y = f2bf(bv[k].y);
            p.z = f2bf(bv[k].z); p.w = f2bf(bv[k].w);
            *(ushort4*)&Bs[buf][w_off + 64 * k * LDSS] = p;
        }
    };

    // ---- prologue: tile 0 -> LDS[0]
    #pragma unroll
    for (int k = 0; k < 4; ++k)
        av[k] = *(const float4*)(aptr + (size_t)(64 * k) * DIM);
    #pragma unroll
    for (int k = 0; k < 2; ++k)
        bv[k] = *(const float4*)(bptr[k]);
    stage(0);
    __syncthreads();

    size_t koff = BK;
    for (int it = 0; it < KITERS; ++it) {
        const int cur = it & 1;

        // issue next-tile loads first (latency hides under ds_read + MFMA)
        if (it + 1 < KITERS) {
            #pragma unroll
            for (int k = 0; k < 4; ++k)
                av[k] = *(const float4*)(aptr + (size_t)(64 * k) * DIM + koff);
            #pragma unroll
            for (int k = 0; k < 2; ++k)
                bv[k] = *(const float4*)(bptr[k] + koff);
            koff += BK;
        }

        // LDS -> fragments -> MFMA on current buffer
        bf16x8 afr[4], bfr[4];
        #pragma unroll
        for (int mt = 0; mt < 4; ++mt)
            afr[mt] = *(const bf16x8*)&As[cur][a_off + mt * 16 * LDSS];
        #pragma unroll
        for (int nt = 0; nt < 4; ++nt)
            bfr[nt] = *(const bf16x8*)&Bs[cur][b_off + nt * 16 * LDSS];

        #pragma unroll
        for (int mt = 0; mt < 4; ++mt)
            #pragma unroll
            for (int nt = 0; nt < 4; ++nt)
                acc[mt][nt] = __builtin_amdgcn_mfma_f32_16x16x32_bf16(
                    afr[mt], bfr[nt], acc[mt][nt], 0, 0, 0);

        // convert + write next tile into the other buffer (no barrier needed before)
        if (it + 1 < KITERS)
            stage(cur ^ 1);

        __syncthreads();   // single barrier per iter (double-buffered)
    }

    // ---- epilogue: atomic-add partial 256x128 tile
    // C/D layout: col = lane&15, row = (lane>>4)*4 + reg
    const int orow0 = wm * 64 + (lane >> 4) * 4;
    const int ocol0 = col0 + wn * 64 + (lane & 15);
    #pragma unroll
    for (int mt = 0; mt < 4; ++mt) {
        #pragma unroll
        for (int nt = 0; nt < 4; ++nt) {
            const int ocol = ocol0 + nt * 16;
            if (ocol < NCLS) {
                #pragma unroll
                for (int e = 0; e < 4; ++e) {
                    const int orow = orow0 + mt * 16 + e;
                    atomicAdd(out + (size_t)orow * NCLS + ocol, acc[mt][nt][e]);
                }
            }
        }
    }
}

extern "C" void kernel_launch(void* const* d_in, const int* in_sizes, int n_in,
                              void* d_out, int out_size, void* d_ws, size_t ws_size,
                              hipStream_t stream) {
    const float* X = (const float*)d_in[0];   // [256, 150528]
    const float* W = (const float*)d_in[1];   // [1000, 150528]
    float* out = (float*)d_out;               // [256, 1000]

    hipMemsetAsync(out, 0, (size_t)out_size * sizeof(float), stream);

    dim3 grid(8, SPLIT);   // x: N tile (0..7), y: D chunk
    dim3 block(512);
    classifier_gemm<<<grid, block, 0, stream>>>(X, W, out);
}